// Round 2
// baseline (1813.460 us; speedup 1.0000x reference)
//
#include <hip/hip_runtime.h>
#include <hip/hip_bf16.h>

// MusicGNN — 3-layer GCN encoder + MLP link predictor.
// N=100000, F_IN=128, HID=64, OUT=32, E=3.2M edges, EL=1M label edges.
// Inputs: float32 (x, weights, biases), int32 (edge indices).
// Output float32: [link_pred (1M) | z (100000*32)] concatenated flat.
//
// Strategy: build CSR-by-destination once (reused for 3 layers), pull-aggregate
// (no float atomics). Fold dinv into GEMM epilogue: h' = (x@W)*dinv[n], then
// agg[n] = dinv[n]*(h'[n] + sum_src h'[src]) + b.

// ---------------- CSR build ----------------

__global__ __launch_bounds__(256) void hist_kernel(const int* __restrict__ colv,
                                                   int* __restrict__ degi, int E) {
    int e = blockIdx.x * 256 + threadIdx.x;
    if (e < E) atomicAdd(&degi[colv[e]], 1);
}

__global__ __launch_bounds__(256) void dinv_kernel(const int* __restrict__ degi,
                                                   float* __restrict__ dinv, int n) {
    int i = blockIdx.x * 256 + threadIdx.x;
    if (i < n) dinv[i] = rsqrtf((float)(degi[i] + 1));  // +1: self loop
}

// two-level exclusive scan over counts (1024 elements / block)
__global__ __launch_bounds__(256) void scan_pass1(const int* __restrict__ counts,
                                                  int* __restrict__ scanned,
                                                  int* __restrict__ bsum, int n) {
    __shared__ int sh[256];
    int base = blockIdx.x * 1024 + threadIdx.x * 4;
    int v[4]; int tsum = 0;
#pragma unroll
    for (int i = 0; i < 4; ++i) { int idx = base + i; v[i] = (idx < n) ? counts[idx] : 0; tsum += v[i]; }
    sh[threadIdx.x] = tsum;
    __syncthreads();
#pragma unroll
    for (int off = 1; off < 256; off <<= 1) {
        int y = (threadIdx.x >= (unsigned)off) ? sh[threadIdx.x - off] : 0;
        __syncthreads();
        sh[threadIdx.x] += y;
        __syncthreads();
    }
    int ex = sh[threadIdx.x] - tsum;  // exclusive prefix of this thread's chunk
#pragma unroll
    for (int i = 0; i < 4; ++i) { int idx = base + i; if (idx < n) scanned[idx] = ex; ex += v[i]; }
    if (threadIdx.x == 255) bsum[blockIdx.x] = sh[255];
}

__global__ void scan_pass2(const int* __restrict__ bsum, int* __restrict__ bbase,
                           int nb, int* __restrict__ offsets_last) {
    if (threadIdx.x == 0 && blockIdx.x == 0) {
        int run = 0;
        for (int i = 0; i < nb; ++i) { bbase[i] = run; run += bsum[i]; }
        offsets_last[0] = run;  // offsets[N] = E
    }
}

__global__ __launch_bounds__(256) void scan_pass3(int* __restrict__ offsets,
                                                  const int* __restrict__ bbase,
                                                  int* __restrict__ cursor, int n) {
    int base = blockIdx.x * 1024 + threadIdx.x * 4;
    int add = bbase[blockIdx.x];
#pragma unroll
    for (int i = 0; i < 4; ++i) {
        int idx = base + i;
        if (idx < n) { int o = offsets[idx] + add; offsets[idx] = o; cursor[idx] = o; }
    }
}

__global__ __launch_bounds__(256) void scatter_edges(const int* __restrict__ rowv,
                                                     const int* __restrict__ colv,
                                                     int* __restrict__ cursor,
                                                     int* __restrict__ edge_src, int E) {
    int e = blockIdx.x * 256 + threadIdx.x;
    if (e < E) {
        int c = colv[e];
        int slot = atomicAdd(&cursor[c], 1);
        edge_src[slot] = rowv[e];
    }
}

// ---------------- GEMM + dinv scale: h'[n][j] = dinv[n] * sum_k in[n][k]*W[k][j] ----------------

template <int K, int NOUT>
__global__ __launch_bounds__(256) void gemm_scale(const float* __restrict__ in_,
                                                  const float* __restrict__ W,
                                                  const float* __restrict__ dinv,
                                                  float* __restrict__ out, int N) {
    __shared__ float Ws[K * NOUT];
    for (int i = threadIdx.x; i < K * NOUT; i += 256) Ws[i] = W[i];
    __syncthreads();
    constexpr int NPB = 256 / NOUT;  // nodes per block
    int node = blockIdx.x * NPB + threadIdx.x / NOUT;
    int j = threadIdx.x % NOUT;
    if (node >= N) return;
    float acc = 0.f;
    const float4* rowp = (const float4*)(in_ + (size_t)node * K);
#pragma unroll
    for (int c = 0; c < K / 4; ++c) {
        float4 v = rowp[c];
        acc = fmaf(v.x, Ws[(c * 4 + 0) * NOUT + j], acc);
        acc = fmaf(v.y, Ws[(c * 4 + 1) * NOUT + j], acc);
        acc = fmaf(v.z, Ws[(c * 4 + 2) * NOUT + j], acc);
        acc = fmaf(v.w, Ws[(c * 4 + 3) * NOUT + j], acc);
    }
    out[(size_t)node * NOUT + j] = acc * dinv[node];
}

// ---------------- Pull aggregation: out[n] = relu?(dinv[n]*(h'[n] + sum h'[src]) + b) ----------------

template <int F, bool RELU>
__global__ __launch_bounds__(256) void agg_pull(const float* __restrict__ h,
                                                const float* __restrict__ dinv,
                                                const float* __restrict__ bias,
                                                const int* __restrict__ edge_src,
                                                const int* __restrict__ offsets,
                                                float* __restrict__ out, int N) {
    int lane = threadIdx.x & 63;
    int wave = blockIdx.x * (256 >> 6) + (threadIdx.x >> 6);
    constexpr int GPW = 64 / F;  // node groups per wave
    int node = wave * GPW + lane / F;
    int f = lane % F;
    if (node >= N) return;
    float dn = dinv[node];
    float acc = h[(size_t)node * F + f];  // self-loop contribution (h' already has dinv[n])
    int beg = offsets[node], end = offsets[node + 1];
    int j = beg;
    for (; j + 4 <= end; j += 4) {
        int s0 = edge_src[j], s1 = edge_src[j + 1], s2 = edge_src[j + 2], s3 = edge_src[j + 3];
        float v0 = h[(size_t)s0 * F + f];
        float v1 = h[(size_t)s1 * F + f];
        float v2 = h[(size_t)s2 * F + f];
        float v3 = h[(size_t)s3 * F + f];
        acc += v0; acc += v1; acc += v2; acc += v3;
    }
    for (; j < end; ++j) acc += h[(size_t)edge_src[j] * F + f];
    float r = acc * dn + bias[f];
    if (RELU) r = fmaxf(r, 0.f);
    out[(size_t)node * F + f] = r;
}

// ---------------- Decode: link_pred[e] = relu(concat(z[a],z[b]) @ lpW1 + lpb1) @ lpW2 + lpb2 ----------------

__global__ __launch_bounds__(256) void decode_kernel(const float* __restrict__ z,  // [N,32]
                                                     const int* __restrict__ eli, int EL,
                                                     const float* __restrict__ lpW1,
                                                     const float* __restrict__ lpb1,
                                                     const float* __restrict__ lpW2,
                                                     const float* __restrict__ lpb2,
                                                     float* __restrict__ out) {
    __shared__ float Ws[64 * 64];
    __shared__ float w2s[64];
    for (int i = threadIdx.x; i < 64 * 64; i += 256) Ws[i] = lpW1[i];
    if (threadIdx.x < 64) w2s[threadIdx.x] = lpW2[threadIdx.x];
    __syncthreads();
    int lane = threadIdx.x & 63;
    int wave = blockIdx.x * 4 + (threadIdx.x >> 6);
    int totalWaves = gridDim.x * 4;
    float b1v = lpb1[lane];
    float b2v = lpb2[0];
    for (int e = wave; e < EL; e += totalWaves) {
        int a = eli[e];
        int b = eli[EL + e];
        int srcnode = (lane < 32) ? a : b;
        float efv = z[(size_t)srcnode * 32 + (lane & 31)];
        float acc = b1v;
#pragma unroll
        for (int k = 0; k < 64; ++k) {
            float ek = __shfl(efv, k, 64);
            acc = fmaf(ek, Ws[k * 64 + lane], acc);
        }
        acc = fmaxf(acc, 0.f);
        float p = acc * w2s[lane];
#pragma unroll
        for (int off = 32; off; off >>= 1) p += __shfl_down(p, off, 64);
        if (lane == 0) out[e] = p + b2v;
    }
}

// ---------------- launch ----------------

extern "C" void kernel_launch(void* const* d_in, const int* in_sizes, int n_in,
                              void* d_out, int out_size, void* d_ws, size_t ws_size,
                              hipStream_t stream) {
    const float* x    = (const float*)d_in[0];
    const int* ei     = (const int*)d_in[1];
    const int* eli    = (const int*)d_in[2];
    const float* W1   = (const float*)d_in[3];
    const float* b1   = (const float*)d_in[4];
    const float* W2   = (const float*)d_in[5];
    const float* b2   = (const float*)d_in[6];
    const float* W3   = (const float*)d_in[7];
    const float* b3   = (const float*)d_in[8];
    const float* lpW1 = (const float*)d_in[9];
    const float* lpb1 = (const float*)d_in[10];
    const float* lpW2 = (const float*)d_in[11];
    const float* lpb2 = (const float*)d_in[12];

    const int N  = in_sizes[0] / 128;   // 100000
    const int E  = in_sizes[1] / 2;     // 3200000
    const int EL = in_sizes[2] / 2;     // 1000000

    // workspace partition (256B aligned chunks); d_ws is poisoned 0xAA each call,
    // every buffer below is fully (re)written each launch.
    char* p = (char*)d_ws;
    auto alloc = [&](size_t bytes) { void* r = (void*)p; p += (bytes + 255) & ~(size_t)255; return r; };
    int*   degi     = (int*)alloc((size_t)N * 4);
    float* dinv     = (float*)alloc((size_t)N * 4);
    int*   offsets  = (int*)alloc((size_t)(N + 1) * 4);
    int*   cursor   = (int*)alloc((size_t)N * 4);
    int*   bsum     = (int*)alloc(256 * 4);
    int*   bbase    = (int*)alloc(256 * 4);
    int*   edge_src = (int*)alloc((size_t)E * 4);
    float* bufG     = (float*)alloc((size_t)N * 64 * 4);
    float* bufZ     = (float*)alloc((size_t)N * 64 * 4);

    const int* rowv = ei;        // edge_index[0] = source
    const int* colv = ei + E;    // edge_index[1] = target

    hipMemsetAsync(degi, 0, (size_t)N * 4, stream);
    hist_kernel<<<(E + 255) / 256, 256, 0, stream>>>(colv, degi, E);
    dinv_kernel<<<(N + 255) / 256, 256, 0, stream>>>(degi, dinv, N);
    int nb = (N + 1023) / 1024;  // 98
    scan_pass1<<<nb, 256, 0, stream>>>(degi, offsets, bsum, N);
    scan_pass2<<<1, 64, 0, stream>>>(bsum, bbase, nb, offsets + N);
    scan_pass3<<<nb, 256, 0, stream>>>(offsets, bbase, cursor, N);
    scatter_edges<<<(E + 255) / 256, 256, 0, stream>>>(rowv, colv, cursor, edge_src, E);

    float* zout = (float*)d_out + EL;   // z lives in the output tail (float32)

    // layer 1: x[N,128] -> bufG h' -> bufZ (relu)
    gemm_scale<128, 64><<<(N + 3) / 4, 256, 0, stream>>>(x, W1, dinv, bufG, N);
    agg_pull<64, true><<<(N + 3) / 4, 256, 0, stream>>>(bufG, dinv, b1, edge_src, offsets, bufZ, N);
    // layer 2
    gemm_scale<64, 64><<<(N + 3) / 4, 256, 0, stream>>>(bufZ, W2, dinv, bufG, N);
    agg_pull<64, true><<<(N + 3) / 4, 256, 0, stream>>>(bufG, dinv, b2, edge_src, offsets, bufZ, N);
    // layer 3: 32-wide, write z directly into d_out tail
    gemm_scale<64, 32><<<(N + 7) / 8, 256, 0, stream>>>(bufZ, W3, dinv, bufG, N);
    agg_pull<32, false><<<(N + 7) / 8, 256, 0, stream>>>(bufG, dinv, b3, edge_src, offsets, zout, N);
    // decode reads z from d_out tail
    decode_kernel<<<2048, 256, 0, stream>>>(zout, eli, EL, lpW1, lpb1, lpW2, lpb2, (float*)d_out);
}

// Round 3
// 1130.872 us; speedup vs baseline: 1.6036x; 1.6036x over previous
//
#include <hip/hip_runtime.h>
#include <hip/hip_bf16.h>

// MusicGNN — 3-layer GCN encoder + MLP link predictor.
// N=100000, F_IN=128, HID=64, OUT=32, E=3.2M edges, EL=1M label edges.
// Inputs: float32 (x, weights, biases), int32 (edge indices).
// Output float32: [link_pred (1M) | z (100000*32)] concatenated flat.
//
// R2: decode rewritten as tiled fp32 GEMM (64-edge tiles, efT staged in LDS,
// 4x4 register tile/thread, fused relu+w2 epilogue). agg unroll 4->8.

// ---------------- CSR build ----------------

__global__ __launch_bounds__(256) void hist_kernel(const int* __restrict__ colv,
                                                   int* __restrict__ degi, int E) {
    int e = blockIdx.x * 256 + threadIdx.x;
    if (e < E) atomicAdd(&degi[colv[e]], 1);
}

__global__ __launch_bounds__(256) void dinv_kernel(const int* __restrict__ degi,
                                                   float* __restrict__ dinv, int n) {
    int i = blockIdx.x * 256 + threadIdx.x;
    if (i < n) dinv[i] = rsqrtf((float)(degi[i] + 1));  // +1: self loop
}

// two-level exclusive scan over counts (1024 elements / block)
__global__ __launch_bounds__(256) void scan_pass1(const int* __restrict__ counts,
                                                  int* __restrict__ scanned,
                                                  int* __restrict__ bsum, int n) {
    __shared__ int sh[256];
    int base = blockIdx.x * 1024 + threadIdx.x * 4;
    int v[4]; int tsum = 0;
#pragma unroll
    for (int i = 0; i < 4; ++i) { int idx = base + i; v[i] = (idx < n) ? counts[idx] : 0; tsum += v[i]; }
    sh[threadIdx.x] = tsum;
    __syncthreads();
#pragma unroll
    for (int off = 1; off < 256; off <<= 1) {
        int y = (threadIdx.x >= (unsigned)off) ? sh[threadIdx.x - off] : 0;
        __syncthreads();
        sh[threadIdx.x] += y;
        __syncthreads();
    }
    int ex = sh[threadIdx.x] - tsum;
#pragma unroll
    for (int i = 0; i < 4; ++i) { int idx = base + i; if (idx < n) scanned[idx] = ex; ex += v[i]; }
    if (threadIdx.x == 255) bsum[blockIdx.x] = sh[255];
}

__global__ void scan_pass2(const int* __restrict__ bsum, int* __restrict__ bbase,
                           int nb, int* __restrict__ offsets_last) {
    if (threadIdx.x == 0 && blockIdx.x == 0) {
        int run = 0;
        for (int i = 0; i < nb; ++i) { bbase[i] = run; run += bsum[i]; }
        offsets_last[0] = run;  // offsets[N] = E
    }
}

__global__ __launch_bounds__(256) void scan_pass3(int* __restrict__ offsets,
                                                  const int* __restrict__ bbase,
                                                  int* __restrict__ cursor, int n) {
    int base = blockIdx.x * 1024 + threadIdx.x * 4;
    int add = bbase[blockIdx.x];
#pragma unroll
    for (int i = 0; i < 4; ++i) {
        int idx = base + i;
        if (idx < n) { int o = offsets[idx] + add; offsets[idx] = o; cursor[idx] = o; }
    }
}

__global__ __launch_bounds__(256) void scatter_edges(const int* __restrict__ rowv,
                                                     const int* __restrict__ colv,
                                                     int* __restrict__ cursor,
                                                     int* __restrict__ edge_src, int E) {
    int e = blockIdx.x * 256 + threadIdx.x;
    if (e < E) {
        int c = colv[e];
        int slot = atomicAdd(&cursor[c], 1);
        edge_src[slot] = rowv[e];
    }
}

// ---------------- GEMM + dinv scale: h'[n][j] = dinv[n] * sum_k in[n][k]*W[k][j] ----------------

template <int K, int NOUT>
__global__ __launch_bounds__(256) void gemm_scale(const float* __restrict__ in_,
                                                  const float* __restrict__ W,
                                                  const float* __restrict__ dinv,
                                                  float* __restrict__ out, int N) {
    __shared__ float Ws[K * NOUT];
    for (int i = threadIdx.x; i < K * NOUT; i += 256) Ws[i] = W[i];
    __syncthreads();
    constexpr int NPB = 256 / NOUT;  // nodes per block
    int node = blockIdx.x * NPB + threadIdx.x / NOUT;
    int j = threadIdx.x % NOUT;
    if (node >= N) return;
    float acc = 0.f;
    const float4* rowp = (const float4*)(in_ + (size_t)node * K);
#pragma unroll
    for (int c = 0; c < K / 4; ++c) {
        float4 v = rowp[c];
        acc = fmaf(v.x, Ws[(c * 4 + 0) * NOUT + j], acc);
        acc = fmaf(v.y, Ws[(c * 4 + 1) * NOUT + j], acc);
        acc = fmaf(v.z, Ws[(c * 4 + 2) * NOUT + j], acc);
        acc = fmaf(v.w, Ws[(c * 4 + 3) * NOUT + j], acc);
    }
    out[(size_t)node * NOUT + j] = acc * dinv[node];
}

// ---------------- Pull aggregation: out[n] = relu?(dinv[n]*(h'[n] + sum h'[src]) + b) ----------------

template <int F, bool RELU>
__global__ __launch_bounds__(256) void agg_pull(const float* __restrict__ h,
                                                const float* __restrict__ dinv,
                                                const float* __restrict__ bias,
                                                const int* __restrict__ edge_src,
                                                const int* __restrict__ offsets,
                                                float* __restrict__ out, int N) {
    int lane = threadIdx.x & 63;
    int wave = blockIdx.x * (256 >> 6) + (threadIdx.x >> 6);
    constexpr int GPW = 64 / F;  // node groups per wave
    int node = wave * GPW + lane / F;
    int f = lane % F;
    if (node >= N) return;
    float dn = dinv[node];
    float acc = h[(size_t)node * F + f];  // self-loop (h' already has dinv[n])
    int beg = offsets[node], end = offsets[node + 1];
    int j = beg;
    for (; j + 8 <= end; j += 8) {
        int s[8];
#pragma unroll
        for (int u = 0; u < 8; ++u) s[u] = edge_src[j + u];
        float v[8];
#pragma unroll
        for (int u = 0; u < 8; ++u) v[u] = h[(size_t)s[u] * F + f];
#pragma unroll
        for (int u = 0; u < 8; ++u) acc += v[u];
    }
    for (; j < end; ++j) acc += h[(size_t)edge_src[j] * F + f];
    float r = acc * dn + bias[f];
    if (RELU) r = fmaxf(r, 0.f);
    out[(size_t)node * F + f] = r;
}

// ---------------- Decode: tiled GEMM. link_pred[e] = relu(ef@W1+b1)@w2 + b2 ----------------
// Tile = 64 edges. efT[k][e] staged transposed in LDS; thread (e0=t&15, j0=t>>4)
// owns a 4x4 acc tile; per k: 2x ds_read_b128 + 16 FMA. Epilogue fuses relu+w2.

#define DTILE 64

__global__ __launch_bounds__(256) void decode_kernel(const float* __restrict__ z,  // [N,32]
                                                     const int* __restrict__ eli, int EL,
                                                     const float* __restrict__ lpW1,
                                                     const float* __restrict__ lpb1,
                                                     const float* __restrict__ lpW2,
                                                     const float* __restrict__ lpb2,
                                                     float* __restrict__ out) {
    __shared__ float Ws[64 * 64];             // W1[k][j]
    __shared__ float efT[64][DTILE + 4];      // [k][e], +4 pad
    __shared__ float red[16][DTILE + 1];      // j-group partials per edge
    for (int i = threadIdx.x; i < 64 * 64; i += 256) Ws[i] = lpW1[i];

    const int t = threadIdx.x;
    const int e0 = t & 15;   // edge block (4 edges)
    const int j0 = t >> 4;   // col block (4 cols)
    float w2r[4], b1r[4];
#pragma unroll
    for (int i = 0; i < 4; ++i) { w2r[i] = lpW2[j0 * 4 + i]; b1r[i] = lpb1[j0 * 4 + i]; }
    const float b2v = lpb2[0];

    // gather role: 2 threads per z-row, 128 rows (64 edges x 2 endpoints)
    const int r = t >> 1;          // row task 0..127
    const int half = t & 1;        // which 64B half of the 128B row
    const int which = r >> 6;      // 0 -> endpoint A, 1 -> endpoint B
    const int eRow = r & 63;

    const int nTiles = EL / DTILE;
    for (int tile = blockIdx.x; tile < nTiles; tile += gridDim.x) {
        // ---- gather phase: stage ef^T into LDS ----
        int node = eli[which * EL + tile * DTILE + eRow];
        const float4* zp = (const float4*)(z + (size_t)node * 32) + half * 4;
#pragma unroll
        for (int q = 0; q < 4; ++q) {
            float4 v = zp[q];
            int kk = which * 32 + half * 16 + q * 4;
            efT[kk + 0][eRow] = v.x;
            efT[kk + 1][eRow] = v.y;
            efT[kk + 2][eRow] = v.z;
            efT[kk + 3][eRow] = v.w;
        }
        __syncthreads();

        // ---- GEMM phase ----
        float acc[4][4];
#pragma unroll
        for (int i = 0; i < 4; ++i)
#pragma unroll
            for (int jj = 0; jj < 4; ++jj) acc[i][jj] = 0.f;
#pragma unroll 8
        for (int k = 0; k < 64; ++k) {
            float4 ef = *(const float4*)&efT[k][e0 * 4];
            float4 wv = *(const float4*)&Ws[k * 64 + j0 * 4];
            acc[0][0] = fmaf(ef.x, wv.x, acc[0][0]);
            acc[0][1] = fmaf(ef.x, wv.y, acc[0][1]);
            acc[0][2] = fmaf(ef.x, wv.z, acc[0][2]);
            acc[0][3] = fmaf(ef.x, wv.w, acc[0][3]);
            acc[1][0] = fmaf(ef.y, wv.x, acc[1][0]);
            acc[1][1] = fmaf(ef.y, wv.y, acc[1][1]);
            acc[1][2] = fmaf(ef.y, wv.z, acc[1][2]);
            acc[1][3] = fmaf(ef.y, wv.w, acc[1][3]);
            acc[2][0] = fmaf(ef.z, wv.x, acc[2][0]);
            acc[2][1] = fmaf(ef.z, wv.y, acc[2][1]);
            acc[2][2] = fmaf(ef.z, wv.z, acc[2][2]);
            acc[2][3] = fmaf(ef.z, wv.w, acc[2][3]);
            acc[3][0] = fmaf(ef.w, wv.x, acc[3][0]);
            acc[3][1] = fmaf(ef.w, wv.y, acc[3][1]);
            acc[3][2] = fmaf(ef.w, wv.z, acc[3][2]);
            acc[3][3] = fmaf(ef.w, wv.w, acc[3][3]);
        }

        // ---- epilogue: relu + dot w2, partial per (j-group, edge) ----
#pragma unroll
        for (int i = 0; i < 4; ++i) {
            float s = 0.f;
#pragma unroll
            for (int jj = 0; jj < 4; ++jj)
                s = fmaf(fmaxf(acc[i][jj] + b1r[jj], 0.f), w2r[jj], s);
            red[j0][e0 * 4 + i] = s;
        }
        __syncthreads();
        if (t < DTILE) {
            float s = 0.f;
#pragma unroll
            for (int g = 0; g < 16; ++g) s += red[g][t];
            out[tile * DTILE + t] = s + b2v;
        }
        // no extra sync needed: next gather writes efT only (all efT reads done
        // before the sync above); red is rewritten only after the next sync.
    }
}

// ---------------- launch ----------------

extern "C" void kernel_launch(void* const* d_in, const int* in_sizes, int n_in,
                              void* d_out, int out_size, void* d_ws, size_t ws_size,
                              hipStream_t stream) {
    const float* x    = (const float*)d_in[0];
    const int* ei     = (const int*)d_in[1];
    const int* eli    = (const int*)d_in[2];
    const float* W1   = (const float*)d_in[3];
    const float* b1   = (const float*)d_in[4];
    const float* W2   = (const float*)d_in[5];
    const float* b2   = (const float*)d_in[6];
    const float* W3   = (const float*)d_in[7];
    const float* b3   = (const float*)d_in[8];
    const float* lpW1 = (const float*)d_in[9];
    const float* lpb1 = (const float*)d_in[10];
    const float* lpW2 = (const float*)d_in[11];
    const float* lpb2 = (const float*)d_in[12];

    const int N  = in_sizes[0] / 128;   // 100000
    const int E  = in_sizes[1] / 2;     // 3200000
    const int EL = in_sizes[2] / 2;     // 1000000

    char* p = (char*)d_ws;
    auto alloc = [&](size_t bytes) { void* r = (void*)p; p += (bytes + 255) & ~(size_t)255; return r; };
    int*   degi     = (int*)alloc((size_t)N * 4);
    float* dinv     = (float*)alloc((size_t)N * 4);
    int*   offsets  = (int*)alloc((size_t)(N + 1) * 4);
    int*   cursor   = (int*)alloc((size_t)N * 4);
    int*   bsum     = (int*)alloc(256 * 4);
    int*   bbase    = (int*)alloc(256 * 4);
    int*   edge_src = (int*)alloc((size_t)E * 4);
    float* bufG     = (float*)alloc((size_t)N * 64 * 4);
    float* bufZ     = (float*)alloc((size_t)N * 64 * 4);

    const int* rowv = ei;        // edge_index[0] = source
    const int* colv = ei + E;    // edge_index[1] = target

    hipMemsetAsync(degi, 0, (size_t)N * 4, stream);
    hist_kernel<<<(E + 255) / 256, 256, 0, stream>>>(colv, degi, E);
    dinv_kernel<<<(N + 255) / 256, 256, 0, stream>>>(degi, dinv, N);
    int nb = (N + 1023) / 1024;  // 98
    scan_pass1<<<nb, 256, 0, stream>>>(degi, offsets, bsum, N);
    scan_pass2<<<1, 64, 0, stream>>>(bsum, bbase, nb, offsets + N);
    scan_pass3<<<nb, 256, 0, stream>>>(offsets, bbase, cursor, N);
    scatter_edges<<<(E + 255) / 256, 256, 0, stream>>>(rowv, colv, cursor, edge_src, E);

    float* zout = (float*)d_out + EL;   // z lives in the output tail (float32)

    // layer 1: x[N,128] -> bufG h' -> bufZ (relu)
    gemm_scale<128, 64><<<(N + 3) / 4, 256, 0, stream>>>(x, W1, dinv, bufG, N);
    agg_pull<64, true><<<(N + 3) / 4, 256, 0, stream>>>(bufG, dinv, b1, edge_src, offsets, bufZ, N);
    // layer 2
    gemm_scale<64, 64><<<(N + 3) / 4, 256, 0, stream>>>(bufZ, W2, dinv, bufG, N);
    agg_pull<64, true><<<(N + 3) / 4, 256, 0, stream>>>(bufG, dinv, b2, edge_src, offsets, bufZ, N);
    // layer 3: 32-wide, write z directly into d_out tail
    gemm_scale<64, 32><<<(N + 7) / 8, 256, 0, stream>>>(bufZ, W3, dinv, bufG, N);
    agg_pull<32, false><<<(N + 7) / 8, 256, 0, stream>>>(bufG, dinv, b3, edge_src, offsets, zout, N);
    // decode reads z from d_out tail
    decode_kernel<<<1024, 256, 0, stream>>>(zout, eli, EL, lpW1, lpb1, lpW2, lpb2, (float*)d_out);
}